// Round 1
// baseline (650.534 us; speedup 1.0000x reference)
//
#include <hip/hip_runtime.h>

#define NROWS 4096
#define NBLK 4
#define DIN 4000
#define DE 128
#define DB 8
#define DLAT 512
#define FANIN 4136
#define KPAD 4224   // 66 * 64
#define NKT 66
#define XC 16000    // NBLK*DIN
#define OUTC 2048   // NBLK*DLAT
#define TC 192      // fallback tail columns: 128 embed + 8 batch + 56 pad

#define PW_GRID 2112
#define PX_THREADS 2162688   // 8,650,752 chunks / 4 per thread = 528*4096
#define PX_GRID 8448         // PX_THREADS / 256

typedef __attribute__((ext_vector_type(8))) short short8;
typedef __attribute__((ext_vector_type(4))) float floatx4;
typedef float __attribute__((ext_vector_type(4))) f32x4;
typedef int   __attribute__((ext_vector_type(4))) i32x4;

__device__ __forceinline__ unsigned short f2bf(float f) {
    unsigned int u = __builtin_bit_cast(unsigned int, f);
    u = (u + 0x7FFFu + ((u >> 16) & 1u)) >> 16;
    return (unsigned short)u;
}

__device__ __forceinline__ void async16(const void* g, void* l) {
    __builtin_amdgcn_global_load_lds(
        (const __attribute__((address_space(1))) void*)g,
        (__attribute__((address_space(3))) void*)l, 16, 0, 0);
}

// ---------------------------------------------------------------------------
// Standalone W-pack (used by fallback path only).
// Pack W (fp32 [4][4136][512]) -> Wp (bf16 [4][512][4224], n-major, K padded).
// ---------------------------------------------------------------------------
__global__ void prep_w(const float* __restrict__ W, unsigned short* __restrict__ Wp) {
    __shared__ unsigned short tile[64 * 68];   // [k 64][n 64], stride 68
    int bid = blockIdx.x;
    int nt = bid & 7;
    int t2 = bid >> 3;
    int kt = t2 % 66;
    int b  = t2 / 66;
    int tid = threadIdx.x;
    int n0 = nt * 64;
    int k0 = kt * 64;
#pragma unroll
    for (int i = 0; i < 4; ++i) {
        int c = i * 256 + tid;
        int r = c >> 4;             // k-row in tile
        int q = (c & 15) * 4;       // n-col
        int pk = k0 + r;
        int wr = (pk < DIN) ? pk : ((pk >= 4032 && pk < 4168) ? pk - 32 : -1);
        float4 v = make_float4(0.f, 0.f, 0.f, 0.f);
        if (wr >= 0)
            v = *reinterpret_cast<const float4*>(W + ((size_t)b * FANIN + wr) * DLAT + n0 + q);
        ushort4 u4 = make_ushort4(f2bf(v.x), f2bf(v.y), f2bf(v.z), f2bf(v.w));
        *reinterpret_cast<ushort4*>(&tile[r * 68 + q]) = u4;
    }
    __syncthreads();
#pragma unroll
    for (int i = 0; i < 2; ++i) {
        int c = i * 256 + tid;
        int nl = c >> 3;            // n within tile
        int kc = c & 7;             // 16B k-chunk
        unsigned short o[8];
#pragma unroll
        for (int j = 0; j < 8; ++j) o[j] = tile[(kc * 8 + j) * 68 + nl];
        *reinterpret_cast<short8*>(Wp + ((size_t)(b * DLAT + n0 + nl)) * KPAD + k0 + kc * 8) =
            *reinterpret_cast<const short8*>(o);
    }
}

// ---------------------------------------------------------------------------
// FAST PATH, fused prep: blocks [0, PW_GRID) pack W; the rest build Xp.
// Xp bf16 [4096][4][4224]: k [0,4000) = mask ? x - mean : 0 ; [4000,4032)=0 ;
// [4032,4160)=embed ; [4160,4168)=batches ; [4168,4224)=0.
//
// prep_x part: each thread owns 4 chunks-of-8 strided by 528*4096 chunks.
// Because the stride is a multiple of 528 (chunks/row-block) AND of 4 (b),
// chunk/b/region-branch are invariant across j; only row += 1024*j. So one
// branch, mean loaded once, and 16 independent x/mask loads in flight.
// x/mask are read-once streams -> nontemporal, keeping Xp L3-resident for
// the GEMM that follows.
// ---------------------------------------------------------------------------
__global__ __launch_bounds__(256, 4) void prep_wx(
    const float* __restrict__ W, unsigned short* __restrict__ Wp,
    const float* __restrict__ x, const int* __restrict__ mask,
    const float* __restrict__ mean, const float* __restrict__ embed,
    const float* __restrict__ batches, unsigned short* __restrict__ Xp) {
    __shared__ unsigned short tile[64 * 68];
    int bid = blockIdx.x;
    int tid = threadIdx.x;

    if (bid < PW_GRID) {
        // ---- W pack (identical math to standalone prep_w) ----
        int nt = bid & 7;
        int t2 = bid >> 3;
        int kt = t2 % 66;
        int b  = t2 / 66;
        int n0 = nt * 64;
        int k0 = kt * 64;
#pragma unroll
        for (int i = 0; i < 4; ++i) {
            int c = i * 256 + tid;
            int r = c >> 4;
            int q = (c & 15) * 4;
            int pk = k0 + r;
            int wr = (pk < DIN) ? pk : ((pk >= 4032 && pk < 4168) ? pk - 32 : -1);
            float4 v = make_float4(0.f, 0.f, 0.f, 0.f);
            if (wr >= 0)
                v = *reinterpret_cast<const float4*>(W + ((size_t)b * FANIN + wr) * DLAT + n0 + q);
            ushort4 u4 = make_ushort4(f2bf(v.x), f2bf(v.y), f2bf(v.z), f2bf(v.w));
            *reinterpret_cast<ushort4*>(&tile[r * 68 + q]) = u4;
        }
        __syncthreads();
#pragma unroll
        for (int i = 0; i < 2; ++i) {
            int c = i * 256 + tid;
            int nl = c >> 3;
            int kc = c & 7;
            unsigned short o[8];
#pragma unroll
            for (int j = 0; j < 8; ++j) o[j] = tile[(kc * 8 + j) * 68 + nl];
            *reinterpret_cast<short8*>(Wp + ((size_t)(b * DLAT + n0 + nl)) * KPAD + k0 + kc * 8) =
                *reinterpret_cast<const short8*>(o);
        }
        return;
    }

    // ---- Xp build ----
    int t = (bid - PW_GRID) * 256 + tid;      // [0, PX_THREADS)
    int chunk = t % 528;                       // invariant across j
    int rb0   = t / 528;                       // j adds 4096
    int b     = rb0 & 3;                       // invariant across j
    int r0    = rb0 >> 2;                      // j adds 1024
    int k     = chunk * 8;

    short8 v[4];
    if (k < DIN) {
        const f32x4* ep = reinterpret_cast<const f32x4*>(mean + b * DIN + k);
        f32x4 e0 = ep[0], e1 = ep[1];
        size_t gi0 = (size_t)r0 * XC + b * DIN + k;
#pragma unroll
        for (int j = 0; j < 4; ++j) {
            size_t gi = gi0 + (size_t)j * 1024 * XC;
            const f32x4* xp = reinterpret_cast<const f32x4*>(x + gi);
            const i32x4* mp = reinterpret_cast<const i32x4*>(mask + gi);
            f32x4 x0 = __builtin_nontemporal_load(xp);
            f32x4 x1 = __builtin_nontemporal_load(xp + 1);
            i32x4 m0 = __builtin_nontemporal_load(mp);
            i32x4 m1 = __builtin_nontemporal_load(mp + 1);
            float f0 = m0.x ? x0.x - e0.x : 0.f;
            float f1 = m0.y ? x0.y - e0.y : 0.f;
            float f2 = m0.z ? x0.z - e0.z : 0.f;
            float f3 = m0.w ? x0.w - e0.w : 0.f;
            float f4 = m1.x ? x1.x - e1.x : 0.f;
            float f5 = m1.y ? x1.y - e1.y : 0.f;
            float f6 = m1.z ? x1.z - e1.z : 0.f;
            float f7 = m1.w ? x1.w - e1.w : 0.f;
            v[j] = (short8){(short)f2bf(f0), (short)f2bf(f1), (short)f2bf(f2), (short)f2bf(f3),
                            (short)f2bf(f4), (short)f2bf(f5), (short)f2bf(f6), (short)f2bf(f7)};
        }
    } else if (k >= 4032 && k < 4160) {
#pragma unroll
        for (int j = 0; j < 4; ++j) {
            int row = r0 + j * 1024;
            const f32x4* ep = reinterpret_cast<const f32x4*>(
                embed + (size_t)row * (NBLK * DE) + b * DE + (k - 4032));
            f32x4 a = ep[0], bb = ep[1];
            v[j] = (short8){(short)f2bf(a.x), (short)f2bf(a.y), (short)f2bf(a.z), (short)f2bf(a.w),
                            (short)f2bf(bb.x), (short)f2bf(bb.y), (short)f2bf(bb.z), (short)f2bf(bb.w)};
        }
    } else if (k == 4160) {
#pragma unroll
        for (int j = 0; j < 4; ++j) {
            int row = r0 + j * 1024;
            const f32x4* bp = reinterpret_cast<const f32x4*>(batches + (size_t)row * DB);
            f32x4 a = bp[0], bb = bp[1];
            v[j] = (short8){(short)f2bf(a.x), (short)f2bf(a.y), (short)f2bf(a.z), (short)f2bf(a.w),
                            (short)f2bf(bb.x), (short)f2bf(bb.y), (short)f2bf(bb.z), (short)f2bf(bb.w)};
        }
    } else {
#pragma unroll
        for (int j = 0; j < 4; ++j) v[j] = (short8){0, 0, 0, 0, 0, 0, 0, 0};
    }

    unsigned short* op = Xp + (size_t)rb0 * KPAD + k;
#pragma unroll
    for (int j = 0; j < 4; ++j)
        *reinterpret_cast<short8*>(op + (size_t)j * 4096 * KPAD) = v[j];
}

// ---------------------------------------------------------------------------
// FAST GEMM (m97 structure): both operands via global_load_lds width-16 into
// XOR-swizzled LDS (physical chunk = logical ^ (row&7), applied on SOURCE
// address so the wave-uniform LDS dest constraint holds). 256 thr = 4 waves
// (2x2), wave tile 64x64, 4x4 frags of 16x16x32 bf16. Grid 512.
// ---------------------------------------------------------------------------
__global__ __launch_bounds__(256, 3) void gemm_x(
    const float* __restrict__ bias, const unsigned short* __restrict__ Wp,
    const unsigned short* __restrict__ Xp, float* __restrict__ out) {
    __shared__ unsigned short Asm_[128 * 64];
    __shared__ unsigned short Bsm_[128 * 64];

    int bid = blockIdx.x;
    int nt  = bid & 3;
    int b   = (bid >> 2) & 3;
    int mt  = bid >> 4;
    int tid  = threadIdx.x;
    int lane = tid & 63;
    int w    = tid >> 6;
    int wm   = w >> 1;
    int wn   = w & 1;
    int quad = lane >> 4;
    int l16  = lane & 15;
    int row0 = mt * 128;
    int n0   = nt * 128;

    floatx4 acc[4][4];
#pragma unroll
    for (int m = 0; m < 4; ++m)
#pragma unroll
        for (int n = 0; n < 4; ++n) acc[m][n] = (floatx4){0.f, 0.f, 0.f, 0.f};

    const unsigned short* Abase = Xp + ((size_t)row0 * NBLK + b) * KPAD;
    const unsigned short* Bbase = Wp + ((size_t)(b * DLAT + n0)) * KPAD;

    for (int kt = 0; kt < NKT; ++kt) {
        int k0 = kt * 64;
        // ---- stage A ----
#pragma unroll
        for (int i = 0; i < 4; ++i) {
            int c  = i * 256 + tid;
            int r  = c >> 3;
            int cg = (c & 7) ^ (r & 7);
            async16(Abase + (size_t)r * (NBLK * KPAD) + k0 + cg * 8, &Asm_[c * 8]);
        }
        // ---- stage B ----
#pragma unroll
        for (int i = 0; i < 4; ++i) {
            int c  = i * 256 + tid;
            int nl = c >> 3;
            int cg = (c & 7) ^ (nl & 7);
            async16(Bbase + (size_t)nl * KPAD + k0 + cg * 8, &Bsm_[c * 8]);
        }
        __syncthreads();
        // ---- MFMA ----
#pragma unroll
        for (int s = 0; s < 2; ++s) {
            short8 af[4], bfr[4];
#pragma unroll
            for (int m = 0; m < 4; ++m) {
                int ar = wm * 64 + m * 16 + l16;
                af[m] = *reinterpret_cast<const short8*>(
                    &Asm_[ar * 64 + (((s * 4 + quad) ^ (ar & 7)) * 8)]);
            }
#pragma unroll
            for (int n = 0; n < 4; ++n) {
                int br = wn * 64 + n * 16 + l16;
                bfr[n] = *reinterpret_cast<const short8*>(
                    &Bsm_[br * 64 + (((s * 4 + quad) ^ (br & 7)) * 8)]);
            }
#pragma unroll
            for (int m = 0; m < 4; ++m)
#pragma unroll
                for (int n = 0; n < 4; ++n)
                    acc[m][n] = __builtin_amdgcn_mfma_f32_16x16x32_bf16(
                        af[m], bfr[n], acc[m][n], 0, 0, 0);
        }
        __syncthreads();
    }

#pragma unroll
    for (int m = 0; m < 4; ++m) {
#pragma unroll
        for (int n = 0; n < 4; ++n) {
            int col_l = wn * 64 + n * 16 + l16;
            float bv = bias[b * DLAT + n0 + col_l];
#pragma unroll
            for (int r = 0; r < 4; ++r) {
                int row_l = wm * 64 + m * 16 + quad * 4 + r;
                float v = acc[m][n][r] + bv;
                v = v >= 0.f ? v : 0.3f * v;
                out[(size_t)(row0 + row_l) * OUTC + b * DLAT + n0 + col_l] = v;
            }
        }
    }
}

// ---------------------------------------------------------------------------
// FALLBACK (ws too small for Xp): round-3 kernels, verified passing.
// ---------------------------------------------------------------------------
__global__ void prep_t(const float* __restrict__ embed, const float* __restrict__ batches,
                       unsigned short* __restrict__ T) {
    int i  = blockIdx.x * 256 + threadIdx.x;
    int t  = i % TC;
    int nb = i / TC;
    int b  = nb & 3;
    int n  = nb >> 2;
    float v = 0.f;
    if (t < DE)            v = embed[(size_t)n * (NBLK * DE) + b * DE + t];
    else if (t < DE + DB)  v = batches[(size_t)n * DB + (t - DE)];
    T[i] = f2bf(v);
}

__global__ __launch_bounds__(256, 3) void gemm_k(
    const float* __restrict__ x, const int* __restrict__ mask,
    const float* __restrict__ mean, const float* __restrict__ bias,
    const unsigned short* __restrict__ Wp, const unsigned short* __restrict__ T,
    float* __restrict__ out) {
    __shared__ unsigned short Asm_[128 * 64];
    __shared__ unsigned short Bsm_[128 * 64];

    int bid = blockIdx.x;
    int nt  = bid & 3;
    int b   = (bid >> 2) & 3;
    int mt  = bid >> 4;
    int tid  = threadIdx.x;
    int lane = tid & 63;
    int w    = tid >> 6;
    int wm   = w >> 1;
    int wn   = w & 1;
    int quad = lane >> 4;
    int l16  = lane & 15;
    int row0 = mt * 128;
    int n0   = nt * 128;

    floatx4 acc[4][4];
#pragma unroll
    for (int m = 0; m < 4; ++m)
#pragma unroll
        for (int n = 0; n < 4; ++n) acc[m][n] = (floatx4){0.f, 0.f, 0.f, 0.f};

    for (int kt = 0; kt < NKT; ++kt) {
        if (kt < 63) {
#pragma unroll
            for (int i = 0; i < 4; ++i) {
                int c  = i * 256 + tid;
                int r  = c >> 3;
                int cg = c & 7;
                int col = kt * 64 + cg * 8;
                short8 v8 = (short8){0, 0, 0, 0, 0, 0, 0, 0};
                if (col < DIN) {
                    size_t gi = (size_t)(row0 + r) * XC + (size_t)b * DIN + col;
                    const float4* xp = reinterpret_cast<const float4*>(x + gi);
                    const int4*   mp = reinterpret_cast<const int4*>(mask + gi);
                    const float4* ep = reinterpret_cast<const float4*>(mean + b * DIN + col);
                    float4 x0 = xp[0], x1 = xp[1];
                    int4   m0 = mp[0], m1 = mp[1];
                    float4 e0 = ep[0], e1 = ep[1];
                    float f0 = m0.x ? x0.x - e0.x : 0.f;
                    float f1 = m0.y ? x0.y - e0.y : 0.f;
                    float f2 = m0.z ? x0.z - e0.z : 0.f;
                    float f3 = m0.w ? x0.w - e0.w : 0.f;
                    float f4 = m1.x ? x1.x - e1.x : 0.f;
                    float f5 = m1.y ? x1.y - e1.y : 0.f;
                    float f6 = m1.z ? x1.z - e1.z : 0.f;
                    float f7 = m1.w ? x1.w - e1.w : 0.f;
                    v8 = (short8){(short)f2bf(f0), (short)f2bf(f1), (short)f2bf(f2),
                                  (short)f2bf(f3), (short)f2bf(f4), (short)f2bf(f5),
                                  (short)f2bf(f6), (short)f2bf(f7)};
                }
                *reinterpret_cast<short8*>(&Asm_[r * 64 + ((cg ^ (r & 7)) * 8)]) = v8;
            }
        } else {
#pragma unroll
            for (int i = 0; i < 4; ++i) {
                int c  = i * 256 + tid;
                int r  = c >> 3;
                int cg = (c & 7) ^ (r & 7);
                async16(T + ((size_t)(row0 + r) * NBLK + b) * TC + (kt - 63) * 64 + cg * 8,
                        &Asm_[c * 8]);
            }
        }
#pragma unroll
        for (int i = 0; i < 4; ++i) {
            int c  = i * 256 + tid;
            int nl = c >> 3;
            int cg = (c & 7) ^ (nl & 7);
            async16(Wp + ((size_t)(b * DLAT + n0 + nl)) * KPAD + kt * 64 + cg * 8,
                    &Bsm_[c * 8]);
        }
        __syncthreads();
#pragma unroll
        for (int s = 0; s < 2; ++s) {
            short8 af[4], bfr[4];
#pragma unroll
            for (int m = 0; m < 4; ++m) {
                int ar = wm * 64 + m * 16 + l16;
                af[m] = *reinterpret_cast<const short8*>(
                    &Asm_[ar * 64 + (((s * 4 + quad) ^ (ar & 7)) * 8)]);
            }
#pragma unroll
            for (int n = 0; n < 4; ++n) {
                int br = wn * 64 + n * 16 + l16;
                bfr[n] = *reinterpret_cast<const short8*>(
                    &Bsm_[br * 64 + (((s * 4 + quad) ^ (br & 7)) * 8)]);
            }
#pragma unroll
            for (int m = 0; m < 4; ++m)
#pragma unroll
                for (int n = 0; n < 4; ++n)
                    acc[m][n] = __builtin_amdgcn_mfma_f32_16x16x32_bf16(
                        af[m], bfr[n], acc[m][n], 0, 0, 0);
        }
        __syncthreads();
    }

#pragma unroll
    for (int m = 0; m < 4; ++m) {
#pragma unroll
        for (int n = 0; n < 4; ++n) {
            int col_l = wn * 64 + n * 16 + l16;
            float bv = bias[b * DLAT + n0 + col_l];
#pragma unroll
            for (int r = 0; r < 4; ++r) {
                int row_l = wm * 64 + m * 16 + quad * 4 + r;
                float v = acc[m][n][r] + bv;
                v = v >= 0.f ? v : 0.3f * v;
                out[(size_t)(row0 + row_l) * OUTC + b * DLAT + n0 + col_l] = v;
            }
        }
    }
}

extern "C" void kernel_launch(void* const* d_in, const int* in_sizes, int n_in,
                              void* d_out, int out_size, void* d_ws, size_t ws_size,
                              hipStream_t stream) {
    const float* x       = (const float*)d_in[0];
    const int*   mask    = (const int*)d_in[1];
    const float* embed   = (const float*)d_in[2];
    const float* batches = (const float*)d_in[3];
    const float* mean    = (const float*)d_in[4];
    const float* W       = (const float*)d_in[5];
    const float* bias    = (const float*)d_in[6];
    float* out = (float*)d_out;

    unsigned short* Wp = (unsigned short*)d_ws;                 // 17.3 MB
    size_t wp_elems = (size_t)NBLK * DLAT * KPAD;               // 8,650,752
    size_t xp_elems = (size_t)NROWS * NBLK * KPAD;              // 69,206,016
    size_t need_fast = (wp_elems + xp_elems) * 2;               // 155,713,536 B

    if (ws_size >= need_fast) {
        unsigned short* Xp = Wp + wp_elems;                     // 138.4 MB
        prep_wx<<<dim3(PW_GRID + PX_GRID), dim3(256), 0, stream>>>(
            W, Wp, x, mask, mean, embed, batches, Xp);
        gemm_x<<<dim3(512), dim3(256), 0, stream>>>(bias, Wp, Xp, out);
    } else {
        prep_w<<<dim3(PW_GRID), dim3(256), 0, stream>>>(W, Wp);
        unsigned short* T = Wp + wp_elems;                      // 6.3 MB
        prep_t<<<dim3(12288), dim3(256), 0, stream>>>(embed, batches, T);
        gemm_k<<<dim3(512), dim3(256), 0, stream>>>(x, mask, mean, bias, Wp, T, out);
    }
}

// Round 2
// 613.292 us; speedup vs baseline: 1.0607x; 1.0607x over previous
//
#include <hip/hip_runtime.h>

#define NROWS 4096
#define NBLK 4
#define DIN 4000
#define DE 128
#define DB 8
#define DLAT 512
#define FANIN 4136
#define KPAD 4224   // 66 * 64
#define NKT 66
#define XC 16000    // NBLK*DIN
#define OUTC 2048   // NBLK*DLAT
#define TC 192      // fallback tail columns: 128 embed + 8 batch + 56 pad

#define PW_GRID 2112

typedef __attribute__((ext_vector_type(8))) short short8;
typedef __attribute__((ext_vector_type(4))) float floatx4;
typedef float __attribute__((ext_vector_type(4))) f32x4;
typedef int   __attribute__((ext_vector_type(4))) i32x4;

__device__ __forceinline__ unsigned short f2bf(float f) {
    unsigned int u = __builtin_bit_cast(unsigned int, f);
    u = (u + 0x7FFFu + ((u >> 16) & 1u)) >> 16;
    return (unsigned short)u;
}

__device__ __forceinline__ void async16(const void* g, void* l) {
    __builtin_amdgcn_global_load_lds(
        (const __attribute__((address_space(1))) void*)g,
        (__attribute__((address_space(3))) void*)l, 16, 0, 0);
}

// ---------------------------------------------------------------------------
// Pack W (fp32 [4][4136][512]) -> Wp (bf16 [4][512][4224], n-major, K padded).
// packed k: [0,4000)=x rows, [4000,4032)=0, [4032,4160)=embed rows,
// [4160,4168)=batch rows, [4168,4224)=0. LDS-transpose: reads+writes coalesced.
// ---------------------------------------------------------------------------
__global__ void prep_w(const float* __restrict__ W, unsigned short* __restrict__ Wp) {
    __shared__ unsigned short tile[64 * 68];   // [k 64][n 64], stride 68
    int bid = blockIdx.x;
    int nt = bid & 7;
    int t2 = bid >> 3;
    int kt = t2 % 66;
    int b  = t2 / 66;
    int tid = threadIdx.x;
    int n0 = nt * 64;
    int k0 = kt * 64;
#pragma unroll
    for (int i = 0; i < 4; ++i) {
        int c = i * 256 + tid;
        int r = c >> 4;             // k-row in tile
        int q = (c & 15) * 4;       // n-col
        int pk = k0 + r;
        int wr = (pk < DIN) ? pk : ((pk >= 4032 && pk < 4168) ? pk - 32 : -1);
        float4 v = make_float4(0.f, 0.f, 0.f, 0.f);
        if (wr >= 0)
            v = *reinterpret_cast<const float4*>(W + ((size_t)b * FANIN + wr) * DLAT + n0 + q);
        ushort4 u4 = make_ushort4(f2bf(v.x), f2bf(v.y), f2bf(v.z), f2bf(v.w));
        *reinterpret_cast<ushort4*>(&tile[r * 68 + q]) = u4;
    }
    __syncthreads();
#pragma unroll
    for (int i = 0; i < 2; ++i) {
        int c = i * 256 + tid;
        int nl = c >> 3;            // n within tile
        int kc = c & 7;             // 16B k-chunk
        unsigned short o[8];
#pragma unroll
        for (int j = 0; j < 8; ++j) o[j] = tile[(kc * 8 + j) * 68 + nl];
        *reinterpret_cast<short8*>(Wp + ((size_t)(b * DLAT + n0 + nl)) * KPAD + k0 + kc * 8) =
            *reinterpret_cast<const short8*>(o);
    }
}

// ---------------------------------------------------------------------------
// FUSED GEMM: no Xp. Grid 256 = 64 mt x 4 b (b = bid&3 -> per-XCD single-b
// Wp panel, L2-near-resident). 512 thr = 8 waves, block tile 64x512, wave
// tile 64x64 (4x4 frags 16x16x32 bf16). Double-buffered LDS (144 KB):
//   Asm [2][64r][64k]  : on-the-fly mask/mean/bf16 A conversion (ds_write)
//   Bsm [2][512n][64k] : Wp via global_load_lds width-16
// Per kt: issue next A x/mask loads (HBM, long latency) FIRST, then next B
// asyncs, then MFMA on current buf (hides latency), then convert+ds_write A,
// one barrier. x+mask read exactly ONCE from HBM -> ~590 MB total traffic.
// ---------------------------------------------------------------------------
__global__ __launch_bounds__(512, 2) void gemm_f(
    const float* __restrict__ x, const int* __restrict__ mask,
    const float* __restrict__ mean, const float* __restrict__ embed,
    const float* __restrict__ batches, const float* __restrict__ bias,
    const unsigned short* __restrict__ Wp, float* __restrict__ out) {
    __shared__ unsigned short Asm_[2][64 * 64];
    __shared__ unsigned short Bsm_[2][512 * 64];

    int bid = blockIdx.x;
    int b   = bid & 3;
    int mt  = bid >> 2;
    int row0 = mt * 64;
    int tid  = threadIdx.x;
    int lane = tid & 63;
    int w    = tid >> 6;        // wave id 0..7 -> col group
    int quad = lane >> 4;
    int l16  = lane & 15;
    int r    = tid >> 3;        // A-stage row 0..63
    int cgl  = tid & 7;         // A-stage logical k-chunk

    const unsigned short* Bbase = Wp + (size_t)b * DLAT * KPAD;

    floatx4 acc[4][4];
#pragma unroll
    for (int m = 0; m < 4; ++m)
#pragma unroll
        for (int n = 0; n < 4; ++n) acc[m][n] = (floatx4){0.f, 0.f, 0.f, 0.f};

    f32x4 xa, xb, ea, eb;
    i32x4 mka, mkb;
    int amode;

#define STAGE_B(NB, KT) do {                                                   \
    int k0_ = (KT) * 64;                                                       \
    _Pragma("unroll")                                                          \
    for (int i_ = 0; i_ < 8; ++i_) {                                           \
        int c_  = i_ * 512 + tid;                                              \
        int nl_ = c_ >> 3;                                                     \
        int cg_ = (c_ & 7) ^ (nl_ & 7);                                        \
        async16(Bbase + (size_t)nl_ * KPAD + k0_ + cg_ * 8,                    \
                &Bsm_[NB][c_ * 8]);                                            \
    }                                                                          \
} while (0)

#define LOAD_A(KT) do {                                                        \
    int col_ = (KT) * 64 + cgl * 8;                                            \
    amode = 3;                                                                 \
    if (col_ < DIN) {                                                          \
        amode = 0;                                                             \
        size_t gi_ = (size_t)(row0 + r) * XC + (size_t)b * DIN + col_;         \
        const f32x4* xp_ = reinterpret_cast<const f32x4*>(x + gi_);            \
        const i32x4* mp_ = reinterpret_cast<const i32x4*>(mask + gi_);         \
        xa  = __builtin_nontemporal_load(xp_);                                 \
        xb  = __builtin_nontemporal_load(xp_ + 1);                             \
        mka = __builtin_nontemporal_load(mp_);                                 \
        mkb = __builtin_nontemporal_load(mp_ + 1);                             \
        const f32x4* ep_ = reinterpret_cast<const f32x4*>(mean + b * DIN + col_); \
        ea = ep_[0]; eb = ep_[1];                                              \
    } else if (col_ >= 4032 && col_ < 4160) {                                  \
        amode = 1;                                                             \
        const f32x4* ep_ = reinterpret_cast<const f32x4*>(                     \
            embed + (size_t)(row0 + r) * (NBLK * DE) + b * DE + (col_ - 4032)); \
        ea = ep_[0]; eb = ep_[1];                                              \
    } else if (col_ == 4160) {                                                 \
        amode = 1;                                                             \
        const f32x4* bp_ = reinterpret_cast<const f32x4*>(                     \
            batches + (size_t)(row0 + r) * DB);                                \
        ea = bp_[0]; eb = bp_[1];                                              \
    }                                                                          \
} while (0)

#define WRITE_A(NB) do {                                                       \
    short8 v8_ = (short8){0, 0, 0, 0, 0, 0, 0, 0};                             \
    if (amode == 0) {                                                          \
        float f0_ = mka.x ? xa.x - ea.x : 0.f;                                 \
        float f1_ = mka.y ? xa.y - ea.y : 0.f;                                 \
        float f2_ = mka.z ? xa.z - ea.z : 0.f;                                 \
        float f3_ = mka.w ? xa.w - ea.w : 0.f;                                 \
        float f4_ = mkb.x ? xb.x - eb.x : 0.f;                                 \
        float f5_ = mkb.y ? xb.y - eb.y : 0.f;                                 \
        float f6_ = mkb.z ? xb.z - eb.z : 0.f;                                 \
        float f7_ = mkb.w ? xb.w - eb.w : 0.f;                                 \
        v8_ = (short8){(short)f2bf(f0_), (short)f2bf(f1_), (short)f2bf(f2_),   \
                       (short)f2bf(f3_), (short)f2bf(f4_), (short)f2bf(f5_),   \
                       (short)f2bf(f6_), (short)f2bf(f7_)};                    \
    } else if (amode == 1) {                                                   \
        v8_ = (short8){(short)f2bf(ea.x), (short)f2bf(ea.y), (short)f2bf(ea.z),\
                       (short)f2bf(ea.w), (short)f2bf(eb.x), (short)f2bf(eb.y),\
                       (short)f2bf(eb.z), (short)f2bf(eb.w)};                  \
    }                                                                          \
    *reinterpret_cast<short8*>(&Asm_[NB][r * 64 + ((cgl ^ (r & 7)) * 8)]) = v8_; \
} while (0)

#define COMPUTE(BUF) do {                                                      \
    _Pragma("unroll")                                                          \
    for (int s_ = 0; s_ < 2; ++s_) {                                           \
        short8 af_[4], bf_[4];                                                 \
        _Pragma("unroll")                                                      \
        for (int m_ = 0; m_ < 4; ++m_) {                                       \
            int ar_ = m_ * 16 + l16;                                           \
            af_[m_] = *reinterpret_cast<const short8*>(                        \
                &Asm_[BUF][ar_ * 64 + (((s_ * 4 + quad) ^ (ar_ & 7)) * 8)]);   \
        }                                                                      \
        _Pragma("unroll")                                                      \
        for (int n_ = 0; n_ < 4; ++n_) {                                       \
            int br_ = w * 64 + n_ * 16 + l16;                                  \
            bf_[n_] = *reinterpret_cast<const short8*>(                        \
                &Bsm_[BUF][br_ * 64 + (((s_ * 4 + quad) ^ (br_ & 7)) * 8)]);   \
        }                                                                      \
        _Pragma("unroll")                                                      \
        for (int m_ = 0; m_ < 4; ++m_)                                         \
            _Pragma("unroll")                                                  \
            for (int n_ = 0; n_ < 4; ++n_)                                     \
                acc[m_][n_] = __builtin_amdgcn_mfma_f32_16x16x32_bf16(         \
                    af_[m_], bf_[n_], acc[m_][n_], 0, 0, 0);                   \
    }                                                                          \
} while (0)

    // prologue: tile 0 into buf 0
    LOAD_A(0);
    STAGE_B(0, 0);
    WRITE_A(0);
    __syncthreads();

    int buf = 0;
    for (int kt = 0; kt < NKT; ++kt) {
        int nb = buf ^ 1;
        if (kt + 1 < NKT) {
            LOAD_A(kt + 1);       // long-latency HBM loads issued first
            STAGE_B(nb, kt + 1);  // L2-resident Wp asyncs
        }
        COMPUTE(buf);             // hides the staging latency
        if (kt + 1 < NKT) WRITE_A(nb);
        __syncthreads();          // drains vmcnt (asyncs) + lgkmcnt
        buf = nb;
    }

#pragma unroll
    for (int m = 0; m < 4; ++m) {
#pragma unroll
        for (int n = 0; n < 4; ++n) {
            int col_l = w * 64 + n * 16 + l16;
            float bv = bias[b * DLAT + col_l];
#pragma unroll
            for (int rr = 0; rr < 4; ++rr) {
                int row_l = m * 16 + quad * 4 + rr;
                float v = acc[m][n][rr] + bv;
                v = v >= 0.f ? v : 0.3f * v;
                out[(size_t)(row0 + row_l) * OUTC + b * DLAT + col_l] = v;
            }
        }
    }
#undef STAGE_B
#undef LOAD_A
#undef WRITE_A
#undef COMPUTE
}

// ---------------------------------------------------------------------------
// FALLBACK (ws too small): round-3 kernels, verified passing.
// ---------------------------------------------------------------------------
__global__ void prep_t(const float* __restrict__ embed, const float* __restrict__ batches,
                       unsigned short* __restrict__ T) {
    int i  = blockIdx.x * 256 + threadIdx.x;
    int t  = i % TC;
    int nb = i / TC;
    int b  = nb & 3;
    int n  = nb >> 2;
    float v = 0.f;
    if (t < DE)            v = embed[(size_t)n * (NBLK * DE) + b * DE + t];
    else if (t < DE + DB)  v = batches[(size_t)n * DB + (t - DE)];
    T[i] = f2bf(v);
}

__global__ __launch_bounds__(256, 3) void gemm_k(
    const float* __restrict__ x, const int* __restrict__ mask,
    const float* __restrict__ mean, const float* __restrict__ bias,
    const unsigned short* __restrict__ Wp, const unsigned short* __restrict__ T,
    float* __restrict__ out) {
    __shared__ unsigned short Asm_[128 * 64];
    __shared__ unsigned short Bsm_[128 * 64];

    int bid = blockIdx.x;
    int nt  = bid & 3;
    int b   = (bid >> 2) & 3;
    int mt  = bid >> 4;
    int tid  = threadIdx.x;
    int lane = tid & 63;
    int w    = tid >> 6;
    int wm   = w >> 1;
    int wn   = w & 1;
    int quad = lane >> 4;
    int l16  = lane & 15;
    int row0 = mt * 128;
    int n0   = nt * 128;

    floatx4 acc[4][4];
#pragma unroll
    for (int m = 0; m < 4; ++m)
#pragma unroll
        for (int n = 0; n < 4; ++n) acc[m][n] = (floatx4){0.f, 0.f, 0.f, 0.f};

    for (int kt = 0; kt < NKT; ++kt) {
        if (kt < 63) {
#pragma unroll
            for (int i = 0; i < 4; ++i) {
                int c  = i * 256 + tid;
                int r  = c >> 3;
                int cg = c & 7;
                int col = kt * 64 + cg * 8;
                short8 v8 = (short8){0, 0, 0, 0, 0, 0, 0, 0};
                if (col < DIN) {
                    size_t gi = (size_t)(row0 + r) * XC + (size_t)b * DIN + col;
                    const float4* xp = reinterpret_cast<const float4*>(x + gi);
                    const int4*   mp = reinterpret_cast<const int4*>(mask + gi);
                    const float4* ep = reinterpret_cast<const float4*>(mean + b * DIN + col);
                    float4 x0 = xp[0], x1 = xp[1];
                    int4   m0 = mp[0], m1 = mp[1];
                    float4 e0 = ep[0], e1 = ep[1];
                    float f0 = m0.x ? x0.x - e0.x : 0.f;
                    float f1 = m0.y ? x0.y - e0.y : 0.f;
                    float f2 = m0.z ? x0.z - e0.z : 0.f;
                    float f3 = m0.w ? x0.w - e0.w : 0.f;
                    float f4 = m1.x ? x1.x - e1.x : 0.f;
                    float f5 = m1.y ? x1.y - e1.y : 0.f;
                    float f6 = m1.z ? x1.z - e1.z : 0.f;
                    float f7 = m1.w ? x1.w - e1.w : 0.f;
                    v8 = (short8){(short)f2bf(f0), (short)f2bf(f1), (short)f2bf(f2),
                                  (short)f2bf(f3), (short)f2bf(f4), (short)f2bf(f5),
                                  (short)f2bf(f6), (short)f2bf(f7)};
                }
                *reinterpret_cast<short8*>(&Asm_[r * 64 + ((cg ^ (r & 7)) * 8)]) = v8;
            }
        } else {
#pragma unroll
            for (int i = 0; i < 4; ++i) {
                int c  = i * 256 + tid;
                int r  = c >> 3;
                int cg = (c & 7) ^ (r & 7);
                async16(T + ((size_t)(row0 + r) * NBLK + b) * TC + (kt - 63) * 64 + cg * 8,
                        &Asm_[c * 8]);
            }
        }
#pragma unroll
        for (int i = 0; i < 4; ++i) {
            int c  = i * 256 + tid;
            int nl = c >> 3;
            int cg = (c & 7) ^ (nl & 7);
            async16(Wp + ((size_t)(b * DLAT + n0 + nl)) * KPAD + kt * 64 + cg * 8,
                    &Bsm_[c * 8]);
        }
        __syncthreads();
#pragma unroll
        for (int s = 0; s < 2; ++s) {
            short8 af[4], bfr[4];
#pragma unroll
            for (int m = 0; m < 4; ++m) {
                int ar = wm * 64 + m * 16 + l16;
                af[m] = *reinterpret_cast<const short8*>(
                    &Asm_[ar * 64 + (((s * 4 + quad) ^ (ar & 7)) * 8)]);
            }
#pragma unroll
            for (int n = 0; n < 4; ++n) {
                int br = wn * 64 + n * 16 + l16;
                bfr[n] = *reinterpret_cast<const short8*>(
                    &Bsm_[br * 64 + (((s * 4 + quad) ^ (br & 7)) * 8)]);
            }
#pragma unroll
            for (int m = 0; m < 4; ++m)
#pragma unroll
                for (int n = 0; n < 4; ++n)
                    acc[m][n] = __builtin_amdgcn_mfma_f32_16x16x32_bf16(
                        af[m], bfr[n], acc[m][n], 0, 0, 0);
        }
        __syncthreads();
    }

#pragma unroll
    for (int m = 0; m < 4; ++m) {
#pragma unroll
        for (int n = 0; n < 4; ++n) {
            int col_l = wn * 64 + n * 16 + l16;
            float bv = bias[b * DLAT + n0 + col_l];
#pragma unroll
            for (int r = 0; r < 4; ++r) {
                int row_l = wm * 64 + m * 16 + quad * 4 + r;
                float v = acc[m][n][r] + bv;
                v = v >= 0.f ? v : 0.3f * v;
                out[(size_t)(row0 + row_l) * OUTC + b * DLAT + n0 + col_l] = v;
            }
        }
    }
}

extern "C" void kernel_launch(void* const* d_in, const int* in_sizes, int n_in,
                              void* d_out, int out_size, void* d_ws, size_t ws_size,
                              hipStream_t stream) {
    const float* x       = (const float*)d_in[0];
    const int*   mask    = (const int*)d_in[1];
    const float* embed   = (const float*)d_in[2];
    const float* batches = (const float*)d_in[3];
    const float* mean    = (const float*)d_in[4];
    const float* W       = (const float*)d_in[5];
    const float* bias    = (const float*)d_in[6];
    float* out = (float*)d_out;

    unsigned short* Wp = (unsigned short*)d_ws;                 // 17.3 MB
    size_t wp_elems = (size_t)NBLK * DLAT * KPAD;               // 8,650,752
    size_t wp_bytes = wp_elems * 2;

    prep_w<<<dim3(PW_GRID), dim3(256), 0, stream>>>(W, Wp);

    if (ws_size >= wp_bytes + (size_t)(NROWS * NBLK * TC) * 2) {
        // fast fused path needs only Wp in ws
        gemm_f<<<dim3(256), dim3(512), 0, stream>>>(
            x, mask, mean, embed, batches, bias, Wp, out);
    } else {
        unsigned short* T = Wp + wp_elems;                      // 6.3 MB
        prep_t<<<dim3(12288), dim3(256), 0, stream>>>(embed, batches, T);
        gemm_k<<<dim3(512), dim3(256), 0, stream>>>(x, mask, mean, bias, Wp, T, out);
    }
}

// Round 3
// 601.335 us; speedup vs baseline: 1.0818x; 1.0199x over previous
//
#include <hip/hip_runtime.h>

#define NROWS 4096
#define NBLK 4
#define DIN 4000
#define DE 128
#define DB 8
#define DLAT 512
#define FANIN 4136
#define KPAD 4224   // 66 * 64
#define NKT 66
#define XC 16000    // NBLK*DIN
#define OUTC 2048   // NBLK*DLAT
#define TC 192      // fallback tail columns: 128 embed + 8 batch + 56 pad

#define PW_GRID 2112

typedef __attribute__((ext_vector_type(8))) short short8;
typedef __attribute__((ext_vector_type(4))) float floatx4;
typedef float __attribute__((ext_vector_type(4))) f32x4;
typedef int   __attribute__((ext_vector_type(4))) i32x4;

__device__ __forceinline__ unsigned short f2bf(float f) {
    unsigned int u = __builtin_bit_cast(unsigned int, f);
    u = (u + 0x7FFFu + ((u >> 16) & 1u)) >> 16;
    return (unsigned short)u;
}

__device__ __forceinline__ void async16(const void* g, void* l) {
    __builtin_amdgcn_global_load_lds(
        (const __attribute__((address_space(1))) void*)g,
        (__attribute__((address_space(3))) void*)l, 16, 0, 0);
}

// ---------------------------------------------------------------------------
// Pack W (fp32 [4][4136][512]) -> Wp (bf16 [4][512][4224], n-major, K padded).
// packed k: [0,4000)=x rows, [4000,4032)=0, [4032,4160)=embed rows,
// [4160,4168)=batch rows, [4168,4224)=0. LDS-transpose: reads+writes coalesced.
// ---------------------------------------------------------------------------
__global__ void prep_w(const float* __restrict__ W, unsigned short* __restrict__ Wp) {
    __shared__ unsigned short tile[64 * 68];   // [k 64][n 64], stride 68
    int bid = blockIdx.x;
    int nt = bid & 7;
    int t2 = bid >> 3;
    int kt = t2 % 66;
    int b  = t2 / 66;
    int tid = threadIdx.x;
    int n0 = nt * 64;
    int k0 = kt * 64;
#pragma unroll
    for (int i = 0; i < 4; ++i) {
        int c = i * 256 + tid;
        int r = c >> 4;             // k-row in tile
        int q = (c & 15) * 4;       // n-col
        int pk = k0 + r;
        int wr = (pk < DIN) ? pk : ((pk >= 4032 && pk < 4168) ? pk - 32 : -1);
        float4 v = make_float4(0.f, 0.f, 0.f, 0.f);
        if (wr >= 0)
            v = *reinterpret_cast<const float4*>(W + ((size_t)b * FANIN + wr) * DLAT + n0 + q);
        ushort4 u4 = make_ushort4(f2bf(v.x), f2bf(v.y), f2bf(v.z), f2bf(v.w));
        *reinterpret_cast<ushort4*>(&tile[r * 68 + q]) = u4;
    }
    __syncthreads();
#pragma unroll
    for (int i = 0; i < 2; ++i) {
        int c = i * 256 + tid;
        int nl = c >> 3;            // n within tile
        int kc = c & 7;             // 16B k-chunk
        unsigned short o[8];
#pragma unroll
        for (int j = 0; j < 8; ++j) o[j] = tile[(kc * 8 + j) * 68 + nl];
        *reinterpret_cast<short8*>(Wp + ((size_t)(b * DLAT + n0 + nl)) * KPAD + k0 + kc * 8) =
            *reinterpret_cast<const short8*>(o);
    }
}

// ---------------------------------------------------------------------------
// FUSED GEMM, round 3: distinct NAMED double buffers (A0/A1/B0/B1) + K-loop
// unrolled x2 so all LDS references are compile-time-constant objects. This
// lets alias analysis prove ds_read(cur) vs global_load_lds(next) disjoint,
// so next-tile loads stay in flight across the MFMA cluster (round-2 version
// used runtime-indexed [2] buffers -> compiler inserted vmcnt(0) before the
// ds_reads -> fully serial per K-step, 7.3k cy/iter).
// Grid 256 = 64 mt x 4 b. 512 thr = 8 waves, block tile 64x512, wave tile
// 64x64 (4x4 frags 16x16x32 bf16). x+mask read exactly once from HBM.
// ---------------------------------------------------------------------------
__global__ __launch_bounds__(512, 2) void gemm_f(
    const float* __restrict__ x, const int* __restrict__ mask,
    const float* __restrict__ mean, const float* __restrict__ embed,
    const float* __restrict__ batches, const float* __restrict__ bias,
    const unsigned short* __restrict__ Wp, float* __restrict__ out) {
    __shared__ unsigned short A0[64 * 64];
    __shared__ unsigned short A1[64 * 64];
    __shared__ unsigned short B0[512 * 64];
    __shared__ unsigned short B1[512 * 64];

    int bid = blockIdx.x;
    int b   = bid & 3;
    int mt  = bid >> 2;
    int row0 = mt * 64;
    int tid  = threadIdx.x;
    int lane = tid & 63;
    int w    = tid >> 6;        // wave id 0..7 -> col group
    int quad = lane >> 4;
    int l16  = lane & 15;
    int r    = tid >> 3;        // A-stage row 0..63
    int cgl  = tid & 7;         // A-stage logical k-chunk

    const unsigned short* Bbase = Wp + (size_t)b * DLAT * KPAD;

    floatx4 acc[4][4];
#pragma unroll
    for (int m = 0; m < 4; ++m)
#pragma unroll
        for (int n = 0; n < 4; ++n) acc[m][n] = (floatx4){0.f, 0.f, 0.f, 0.f};

    f32x4 xa, xb, ea, eb;
    i32x4 mka, mkb;
    int amode;

#define STAGE_B(BN, KT) do {                                                   \
    int k0_ = (KT) * 64;                                                       \
    _Pragma("unroll")                                                          \
    for (int i_ = 0; i_ < 8; ++i_) {                                           \
        int c_  = i_ * 512 + tid;                                              \
        int nl_ = c_ >> 3;                                                     \
        int cg_ = (c_ & 7) ^ (nl_ & 7);                                        \
        async16(Bbase + (size_t)nl_ * KPAD + k0_ + cg_ * 8, &BN[c_ * 8]);      \
    }                                                                          \
} while (0)

#define LOAD_A(KT) do {                                                        \
    int col_ = (KT) * 64 + cgl * 8;                                            \
    amode = 3;                                                                 \
    if (col_ < DIN) {                                                          \
        amode = 0;                                                             \
        size_t gi_ = (size_t)(row0 + r) * XC + (size_t)b * DIN + col_;         \
        const f32x4* xp_ = reinterpret_cast<const f32x4*>(x + gi_);            \
        const i32x4* mp_ = reinterpret_cast<const i32x4*>(mask + gi_);         \
        xa  = __builtin_nontemporal_load(xp_);                                 \
        xb  = __builtin_nontemporal_load(xp_ + 1);                             \
        mka = __builtin_nontemporal_load(mp_);                                 \
        mkb = __builtin_nontemporal_load(mp_ + 1);                             \
        const f32x4* ep_ = reinterpret_cast<const f32x4*>(mean + b * DIN + col_); \
        ea = ep_[0]; eb = ep_[1];                                              \
    } else if (col_ >= 4032 && col_ < 4160) {                                  \
        amode = 1;                                                             \
        const f32x4* ep_ = reinterpret_cast<const f32x4*>(                     \
            embed + (size_t)(row0 + r) * (NBLK * DE) + b * DE + (col_ - 4032)); \
        ea = ep_[0]; eb = ep_[1];                                              \
    } else if (col_ == 4160) {                                                 \
        amode = 1;                                                             \
        const f32x4* bp_ = reinterpret_cast<const f32x4*>(                     \
            batches + (size_t)(row0 + r) * DB);                                \
        ea = bp_[0]; eb = bp_[1];                                              \
    }                                                                          \
} while (0)

#define WRITE_A(AN) do {                                                       \
    short8 v8_ = (short8){0, 0, 0, 0, 0, 0, 0, 0};                             \
    if (amode == 0) {                                                          \
        float f0_ = mka.x ? xa.x - ea.x : 0.f;                                 \
        float f1_ = mka.y ? xa.y - ea.y : 0.f;                                 \
        float f2_ = mka.z ? xa.z - ea.z : 0.f;                                 \
        float f3_ = mka.w ? xa.w - ea.w : 0.f;                                 \
        float f4_ = mkb.x ? xb.x - eb.x : 0.f;                                 \
        float f5_ = mkb.y ? xb.y - eb.y : 0.f;                                 \
        float f6_ = mkb.z ? xb.z - eb.z : 0.f;                                 \
        float f7_ = mkb.w ? xb.w - eb.w : 0.f;                                 \
        v8_ = (short8){(short)f2bf(f0_), (short)f2bf(f1_), (short)f2bf(f2_),   \
                       (short)f2bf(f3_), (short)f2bf(f4_), (short)f2bf(f5_),   \
                       (short)f2bf(f6_), (short)f2bf(f7_)};                    \
    } else if (amode == 1) {                                                   \
        v8_ = (short8){(short)f2bf(ea.x), (short)f2bf(ea.y), (short)f2bf(ea.z),\
                       (short)f2bf(ea.w), (short)f2bf(eb.x), (short)f2bf(eb.y),\
                       (short)f2bf(eb.z), (short)f2bf(eb.w)};                  \
    }                                                                          \
    *reinterpret_cast<short8*>(&AN[r * 64 + ((cgl ^ (r & 7)) * 8)]) = v8_;     \
} while (0)

#define COMPUTE(AN, BN) do {                                                   \
    _Pragma("unroll")                                                          \
    for (int s_ = 0; s_ < 2; ++s_) {                                           \
        short8 af_[4], bf_[4];                                                 \
        _Pragma("unroll")                                                      \
        for (int m_ = 0; m_ < 4; ++m_) {                                       \
            int ar_ = m_ * 16 + l16;                                           \
            af_[m_] = *reinterpret_cast<const short8*>(                        \
                &AN[ar_ * 64 + (((s_ * 4 + quad) ^ (ar_ & 7)) * 8)]);          \
        }                                                                      \
        _Pragma("unroll")                                                      \
        for (int n_ = 0; n_ < 4; ++n_) {                                       \
            int br_ = w * 64 + n_ * 16 + l16;                                  \
            bf_[n_] = *reinterpret_cast<const short8*>(                        \
                &BN[br_ * 64 + (((s_ * 4 + quad) ^ (br_ & 7)) * 8)]);          \
        }                                                                      \
        _Pragma("unroll")                                                      \
        for (int m_ = 0; m_ < 4; ++m_)                                         \
            _Pragma("unroll")                                                  \
            for (int n_ = 0; n_ < 4; ++n_)                                     \
                acc[m_][n_] = __builtin_amdgcn_mfma_f32_16x16x32_bf16(         \
                    af_[m_], bf_[n_], acc[m_][n_], 0, 0, 0);                   \
    }                                                                          \
} while (0)

    // prologue: tile 0 -> buf 0
    LOAD_A(0);
    STAGE_B(B0, 0);
    WRITE_A(A0);
    __syncthreads();

    // NKT = 66 (even). Even phase: compute buf0(kt), stage buf1(kt+1) --
    // kt+1 <= 65 always valid. Odd phase: compute buf1(kt+1), stage
    // buf0(kt+2) unless kt+2 == NKT.
    for (int kt = 0; kt < NKT; kt += 2) {
        // even phase
        LOAD_A(kt + 1);
        STAGE_B(B1, kt + 1);
        COMPUTE(A0, B0);
        WRITE_A(A1);
        __syncthreads();
        // odd phase
        if (kt + 2 < NKT) {
            LOAD_A(kt + 2);
            STAGE_B(B0, kt + 2);
        }
        COMPUTE(A1, B1);
        if (kt + 2 < NKT) WRITE_A(A0);
        __syncthreads();
    }

#pragma unroll
    for (int m = 0; m < 4; ++m) {
#pragma unroll
        for (int n = 0; n < 4; ++n) {
            int col_l = w * 64 + n * 16 + l16;
            float bv = bias[b * DLAT + col_l];
#pragma unroll
            for (int rr = 0; rr < 4; ++rr) {
                int row_l = m * 16 + quad * 4 + rr;
                float v = acc[m][n][rr] + bv;
                v = v >= 0.f ? v : 0.3f * v;
                out[(size_t)(row0 + row_l) * OUTC + b * DLAT + col_l] = v;
            }
        }
    }
#undef STAGE_B
#undef LOAD_A
#undef WRITE_A
#undef COMPUTE
}

// ---------------------------------------------------------------------------
// FALLBACK (ws too small): round-3 kernels, verified passing.
// ---------------------------------------------------------------------------
__global__ void prep_t(const float* __restrict__ embed, const float* __restrict__ batches,
                       unsigned short* __restrict__ T) {
    int i  = blockIdx.x * 256 + threadIdx.x;
    int t  = i % TC;
    int nb = i / TC;
    int b  = nb & 3;
    int n  = nb >> 2;
    float v = 0.f;
    if (t < DE)            v = embed[(size_t)n * (NBLK * DE) + b * DE + t];
    else if (t < DE + DB)  v = batches[(size_t)n * DB + (t - DE)];
    T[i] = f2bf(v);
}

__global__ __launch_bounds__(256, 3) void gemm_k(
    const float* __restrict__ x, const int* __restrict__ mask,
    const float* __restrict__ mean, const float* __restrict__ bias,
    const unsigned short* __restrict__ Wp, const unsigned short* __restrict__ T,
    float* __restrict__ out) {
    __shared__ unsigned short Asm_[128 * 64];
    __shared__ unsigned short Bsm_[128 * 64];

    int bid = blockIdx.x;
    int nt  = bid & 3;
    int b   = (bid >> 2) & 3;
    int mt  = bid >> 4;
    int tid  = threadIdx.x;
    int lane = tid & 63;
    int w    = tid >> 6;
    int wm   = w >> 1;
    int wn   = w & 1;
    int quad = lane >> 4;
    int l16  = lane & 15;
    int row0 = mt * 128;
    int n0   = nt * 128;

    floatx4 acc[4][4];
#pragma unroll
    for (int m = 0; m < 4; ++m)
#pragma unroll
        for (int n = 0; n < 4; ++n) acc[m][n] = (floatx4){0.f, 0.f, 0.f, 0.f};

    for (int kt = 0; kt < NKT; ++kt) {
        if (kt < 63) {
#pragma unroll
            for (int i = 0; i < 4; ++i) {
                int c  = i * 256 + tid;
                int r  = c >> 3;
                int cg = c & 7;
                int col = kt * 64 + cg * 8;
                short8 v8 = (short8){0, 0, 0, 0, 0, 0, 0, 0};
                if (col < DIN) {
                    size_t gi = (size_t)(row0 + r) * XC + (size_t)b * DIN + col;
                    const float4* xp = reinterpret_cast<const float4*>(x + gi);
                    const int4*   mp = reinterpret_cast<const int4*>(mask + gi);
                    const float4* ep = reinterpret_cast<const float4*>(mean + b * DIN + col);
                    float4 x0 = xp[0], x1 = xp[1];
                    int4   m0 = mp[0], m1 = mp[1];
                    float4 e0 = ep[0], e1 = ep[1];
                    float f0 = m0.x ? x0.x - e0.x : 0.f;
                    float f1 = m0.y ? x0.y - e0.y : 0.f;
                    float f2 = m0.z ? x0.z - e0.z : 0.f;
                    float f3 = m0.w ? x0.w - e0.w : 0.f;
                    float f4 = m1.x ? x1.x - e1.x : 0.f;
                    float f5 = m1.y ? x1.y - e1.y : 0.f;
                    float f6 = m1.z ? x1.z - e1.z : 0.f;
                    float f7 = m1.w ? x1.w - e1.w : 0.f;
                    v8 = (short8){(short)f2bf(f0), (short)f2bf(f1), (short)f2bf(f2),
                                  (short)f2bf(f3), (short)f2bf(f4), (short)f2bf(f5),
                                  (short)f2bf(f6), (short)f2bf(f7)};
                }
                *reinterpret_cast<short8*>(&Asm_[r * 64 + ((cg ^ (r & 7)) * 8)]) = v8;
            }
        } else {
#pragma unroll
            for (int i = 0; i < 4; ++i) {
                int c  = i * 256 + tid;
                int r  = c >> 3;
                int cg = (c & 7) ^ (r & 7);
                async16(T + ((size_t)(row0 + r) * NBLK + b) * TC + (kt - 63) * 64 + cg * 8,
                        &Asm_[c * 8]);
            }
        }
#pragma unroll
        for (int i = 0; i < 4; ++i) {
            int c  = i * 256 + tid;
            int nl = c >> 3;
            int cg = (c & 7) ^ (nl & 7);
            async16(Wp + ((size_t)(b * DLAT + n0 + nl)) * KPAD + kt * 64 + cg * 8,
                    &Bsm_[c * 8]);
        }
        __syncthreads();
#pragma unroll
        for (int s = 0; s < 2; ++s) {
            short8 af[4], bfr[4];
#pragma unroll
            for (int m = 0; m < 4; ++m) {
                int ar = wm * 64 + m * 16 + l16;
                af[m] = *reinterpret_cast<const short8*>(
                    &Asm_[ar * 64 + (((s * 4 + quad) ^ (ar & 7)) * 8)]);
            }
#pragma unroll
            for (int n = 0; n < 4; ++n) {
                int br = wn * 64 + n * 16 + l16;
                bfr[n] = *reinterpret_cast<const short8*>(
                    &Bsm_[br * 64 + (((s * 4 + quad) ^ (br & 7)) * 8)]);
            }
#pragma unroll
            for (int m = 0; m < 4; ++m)
#pragma unroll
                for (int n = 0; n < 4; ++n)
                    acc[m][n] = __builtin_amdgcn_mfma_f32_16x16x32_bf16(
                        af[m], bfr[n], acc[m][n], 0, 0, 0);
        }
        __syncthreads();
    }

#pragma unroll
    for (int m = 0; m < 4; ++m) {
#pragma unroll
        for (int n = 0; n < 4; ++n) {
            int col_l = wn * 64 + n * 16 + l16;
            float bv = bias[b * DLAT + n0 + col_l];
#pragma unroll
            for (int r = 0; r < 4; ++r) {
                int row_l = wm * 64 + m * 16 + quad * 4 + r;
                float v = acc[m][n][r] + bv;
                v = v >= 0.f ? v : 0.3f * v;
                out[(size_t)(row0 + row_l) * OUTC + b * DLAT + n0 + col_l] = v;
            }
        }
    }
}

extern "C" void kernel_launch(void* const* d_in, const int* in_sizes, int n_in,
                              void* d_out, int out_size, void* d_ws, size_t ws_size,
                              hipStream_t stream) {
    const float* x       = (const float*)d_in[0];
    const int*   mask    = (const int*)d_in[1];
    const float* embed   = (const float*)d_in[2];
    const float* batches = (const float*)d_in[3];
    const float* mean    = (const float*)d_in[4];
    const float* W       = (const float*)d_in[5];
    const float* bias    = (const float*)d_in[6];
    float* out = (float*)d_out;

    unsigned short* Wp = (unsigned short*)d_ws;                 // 17.3 MB
    size_t wp_elems = (size_t)NBLK * DLAT * KPAD;               // 8,650,752
    size_t wp_bytes = wp_elems * 2;

    prep_w<<<dim3(PW_GRID), dim3(256), 0, stream>>>(W, Wp);

    if (ws_size >= wp_bytes + (size_t)(NROWS * NBLK * TC) * 2) {
        // fast fused path needs only Wp in ws
        gemm_f<<<dim3(256), dim3(512), 0, stream>>>(
            x, mask, mean, embed, batches, bias, Wp, out);
    } else {
        unsigned short* T = Wp + wp_elems;                      // 6.3 MB
        prep_t<<<dim3(12288), dim3(256), 0, stream>>>(embed, batches, T);
        gemm_k<<<dim3(512), dim3(256), 0, stream>>>(x, mask, mean, bias, Wp, T, out);
    }
}

// Round 5
// 584.736 us; speedup vs baseline: 1.1125x; 1.0284x over previous
//
#include <hip/hip_runtime.h>

#define NROWS 4096
#define NBLK 4
#define DIN 4000
#define DE 128
#define DB 8
#define DLAT 512
#define FANIN 4136
#define KPAD 4224   // 66 * 64
#define NKT 66
#define XC 16000    // NBLK*DIN
#define OUTC 2048   // NBLK*DLAT
#define TC 192      // fallback tail columns
#define T2C 256     // fast-path tail cols: 32 x-tail + 32 pad + 128 embed + 8 batch + 56 pad

#define PW_GRID 2112
#define PT2_GRID 2048   // 4096*4*32 chunks / 256

typedef __attribute__((ext_vector_type(8))) short short8;
typedef __attribute__((ext_vector_type(4))) float floatx4;
typedef float __attribute__((ext_vector_type(4))) f32x4;
typedef int   __attribute__((ext_vector_type(4))) i32x4;

__device__ __forceinline__ unsigned short f2bf(float f) {
    unsigned int u = __builtin_bit_cast(unsigned int, f);
    u = (u + 0x7FFFu + ((u >> 16) & 1u)) >> 16;
    return (unsigned short)u;
}

__device__ __forceinline__ void async16(const void* g, void* l) {
    __builtin_amdgcn_global_load_lds(
        (const __attribute__((address_space(1))) void*)g,
        (__attribute__((address_space(3))) void*)l, 16, 0, 0);
}

#define SCHED0 __builtin_amdgcn_sched_barrier(0)
#define BAR    __builtin_amdgcn_s_barrier()
#define WAITVM6 asm volatile("s_waitcnt vmcnt(6)" ::: "memory")
#define WAITVM0 asm volatile("s_waitcnt vmcnt(0)" ::: "memory")
#define WAITLG  asm volatile("s_waitcnt lgkmcnt(0)" ::: "memory")

// ---------------------------------------------------------------------------
// Fused prep: blocks [0,2112) pack W (fp32 [4][4136][512] -> bf16
// [4][512][4224] n-major, K padded); blocks [2112,4160) build T2
// (bf16 [4096][4][256] = packed cols 3968..4223: 32 x-tail (mask/mean) +
// 32 zero + 128 embed + 8 batch + 56 zero).
// ---------------------------------------------------------------------------
__global__ void prep_wt(const float* __restrict__ W, unsigned short* __restrict__ Wp,
                        const float* __restrict__ x, const int* __restrict__ mask,
                        const float* __restrict__ mean, const float* __restrict__ embed,
                        const float* __restrict__ batches, unsigned short* __restrict__ T2) {
    __shared__ unsigned short tile[64 * 68];
    int bid = blockIdx.x;
    int tid = threadIdx.x;

    if (bid < PW_GRID) {
        int nt = bid & 7;
        int t2 = bid >> 3;
        int kt = t2 % 66;
        int b  = t2 / 66;
        int n0 = nt * 64;
        int k0 = kt * 64;
#pragma unroll
        for (int i = 0; i < 4; ++i) {
            int c = i * 256 + tid;
            int r = c >> 4;
            int q = (c & 15) * 4;
            int pk = k0 + r;
            int wr = (pk < DIN) ? pk : ((pk >= 4032 && pk < 4168) ? pk - 32 : -1);
            float4 v = make_float4(0.f, 0.f, 0.f, 0.f);
            if (wr >= 0)
                v = *reinterpret_cast<const float4*>(W + ((size_t)b * FANIN + wr) * DLAT + n0 + q);
            ushort4 u4 = make_ushort4(f2bf(v.x), f2bf(v.y), f2bf(v.z), f2bf(v.w));
            *reinterpret_cast<ushort4*>(&tile[r * 68 + q]) = u4;
        }
        __syncthreads();
#pragma unroll
        for (int i = 0; i < 2; ++i) {
            int c = i * 256 + tid;
            int nl = c >> 3;
            int kc = c & 7;
            unsigned short o[8];
#pragma unroll
            for (int j = 0; j < 8; ++j) o[j] = tile[(kc * 8 + j) * 68 + nl];
            *reinterpret_cast<short8*>(Wp + ((size_t)(b * DLAT + n0 + nl)) * KPAD + k0 + kc * 8) =
                *reinterpret_cast<const short8*>(o);
        }
        return;
    }

    // ---- T2 build ----
    int i  = (bid - PW_GRID) * 256 + tid;   // [0, 4096*4*32)
    int tc = i & 31;                         // chunk of 8 within 256 cols
    int rb = i >> 5;                         // row*4 + b
    int b  = rb & 3;
    int row = rb >> 2;
    int k  = tc * 8;
    short8 v8 = (short8){0, 0, 0, 0, 0, 0, 0, 0};
    if (k < 32) {
        int col = 3968 + k;                  // x-tail cols 3968..3999
        size_t gi = (size_t)row * XC + (size_t)b * DIN + col;
        const f32x4* xp = reinterpret_cast<const f32x4*>(x + gi);
        const i32x4* mp = reinterpret_cast<const i32x4*>(mask + gi);
        const f32x4* ep = reinterpret_cast<const f32x4*>(mean + b * DIN + col);
        f32x4 x0 = xp[0], x1 = xp[1];
        i32x4 m0 = mp[0], m1 = mp[1];
        f32x4 e0 = ep[0], e1 = ep[1];
        float f0 = m0.x ? x0.x - e0.x : 0.f;
        float f1 = m0.y ? x0.y - e0.y : 0.f;
        float f2 = m0.z ? x0.z - e0.z : 0.f;
        float f3 = m0.w ? x0.w - e0.w : 0.f;
        float f4 = m1.x ? x1.x - e1.x : 0.f;
        float f5 = m1.y ? x1.y - e1.y : 0.f;
        float f6 = m1.z ? x1.z - e1.z : 0.f;
        float f7 = m1.w ? x1.w - e1.w : 0.f;
        v8 = (short8){(short)f2bf(f0), (short)f2bf(f1), (short)f2bf(f2), (short)f2bf(f3),
                      (short)f2bf(f4), (short)f2bf(f5), (short)f2bf(f6), (short)f2bf(f7)};
    } else if (k >= 64 && k < 192) {
        const f32x4* ep = reinterpret_cast<const f32x4*>(
            embed + (size_t)row * (NBLK * DE) + b * DE + (k - 64));
        f32x4 a = ep[0], bb = ep[1];
        v8 = (short8){(short)f2bf(a.x), (short)f2bf(a.y), (short)f2bf(a.z), (short)f2bf(a.w),
                      (short)f2bf(bb.x), (short)f2bf(bb.y), (short)f2bf(bb.z), (short)f2bf(bb.w)};
    } else if (k == 192) {
        const f32x4* bp = reinterpret_cast<const f32x4*>(batches + (size_t)row * DB);
        f32x4 a = bp[0], bb = bp[1];
        v8 = (short8){(short)f2bf(a.x), (short)f2bf(a.y), (short)f2bf(a.z), (short)f2bf(a.w),
                      (short)f2bf(bb.x), (short)f2bf(bb.y), (short)f2bf(bb.z), (short)f2bf(bb.w)};
    }
    *reinterpret_cast<short8*>(T2 + (size_t)rb * T2C + k) = v8;
}

// ---------------------------------------------------------------------------
// FUSED GEMM (T3+T4): counted-vmcnt pipeline, ONE raw s_barrier per K-step,
// prefetch reg-loads stay in flight ACROSS the barrier. Main loop kt=0..61
// branchless (uniform VMEM signature: 6 reg loads + 8 B-asyncs per iter ->
// static vmcnt). Tail kt=62..65 staged from T2 via global_load_lds.
// Grid 256 = 64 mt x 4 b. 512 thr = 8 waves, block 64x512, wave 64x64.
// Steady-state FIFO invariant at barrier: [R(kt+2):6] in flight; B-asyncs
// drained by vmcnt(6); ds_writes drained by lgkmcnt(0).
// (Resubmitted unchanged after round-4 infra failure; audit found no
// divergent-barrier or vmcnt-accounting hazard.)
// ---------------------------------------------------------------------------
__global__ __launch_bounds__(512, 2) void gemm_f(
    const float* __restrict__ x, const int* __restrict__ mask,
    const float* __restrict__ mean, const float* __restrict__ bias,
    const unsigned short* __restrict__ Wp, const unsigned short* __restrict__ T2,
    float* __restrict__ out) {
    __shared__ unsigned short A0[64 * 64];
    __shared__ unsigned short A1[64 * 64];
    __shared__ unsigned short B0[512 * 64];
    __shared__ unsigned short B1[512 * 64];

    int bid = blockIdx.x;
    int b   = bid & 3;
    int mt  = bid >> 2;
    int row0 = mt * 64;
    int tid  = threadIdx.x;
    int lane = tid & 63;
    int w    = tid >> 6;        // wave id 0..7 -> col group
    int quad = lane >> 4;
    int l16  = lane & 15;
    int r    = tid >> 3;        // A-stage row 0..63
    int cgl  = tid & 7;         // A-stage logical k-chunk

    const unsigned short* Bbase = Wp + (size_t)b * DLAT * KPAD;

    floatx4 acc[4][4];
#pragma unroll
    for (int m = 0; m < 4; ++m)
#pragma unroll
        for (int n = 0; n < 4; ++n) acc[m][n] = (floatx4){0.f, 0.f, 0.f, 0.f};

    f32x4 xa, xb, ea, eb;
    i32x4 mka, mkb;

#define STAGE_B(BN, KT) do {                                                   \
    int k0_ = (KT) * 64;                                                       \
    _Pragma("unroll")                                                          \
    for (int i_ = 0; i_ < 8; ++i_) {                                           \
        int c_  = i_ * 512 + tid;                                              \
        int nl_ = c_ >> 3;                                                     \
        int cg_ = (c_ & 7) ^ (nl_ & 7);                                        \
        async16(Bbase + (size_t)nl_ * KPAD + k0_ + cg_ * 8, &BN[c_ * 8]);      \
    }                                                                          \
} while (0)

#define STAGE_T(AN, KT) do {                                                   \
    async16(T2 + ((size_t)(row0 + r) * NBLK + b) * T2C + ((KT) - 62) * 64 +    \
                ((cgl ^ (r & 7)) * 8),                                         \
            &AN[tid * 8]);                                                     \
} while (0)

// main-loop A load: KT <= 61 guaranteed -> col+8 <= 3968 < DIN, branchless.
#define LOAD_A(KT) do {                                                        \
    int col_ = (KT) * 64 + cgl * 8;                                            \
    size_t gi_ = (size_t)(row0 + r) * XC + (size_t)b * DIN + col_;             \
    const f32x4* xp_ = reinterpret_cast<const f32x4*>(x + gi_);                \
    const i32x4* mp_ = reinterpret_cast<const i32x4*>(mask + gi_);             \
    xa  = __builtin_nontemporal_load(xp_);                                     \
    xb  = __builtin_nontemporal_load(xp_ + 1);                                 \
    mka = __builtin_nontemporal_load(mp_);                                     \
    mkb = __builtin_nontemporal_load(mp_ + 1);                                 \
    const f32x4* ep_ = reinterpret_cast<const f32x4*>(mean + b * DIN + col_);  \
    ea = ep_[0]; eb = ep_[1];                                                  \
} while (0)

#define WRITE_A(AN) do {                                                       \
    float f0_ = mka.x ? xa.x - ea.x : 0.f;                                     \
    float f1_ = mka.y ? xa.y - ea.y : 0.f;                                     \
    float f2_ = mka.z ? xa.z - ea.z : 0.f;                                     \
    float f3_ = mka.w ? xa.w - ea.w : 0.f;                                     \
    float f4_ = mkb.x ? xb.x - eb.x : 0.f;                                     \
    float f5_ = mkb.y ? xb.y - eb.y : 0.f;                                     \
    float f6_ = mkb.z ? xb.z - eb.z : 0.f;                                     \
    float f7_ = mkb.w ? xb.w - eb.w : 0.f;                                     \
    short8 v8_ = (short8){(short)f2bf(f0_), (short)f2bf(f1_), (short)f2bf(f2_),\
                          (short)f2bf(f3_), (short)f2bf(f4_), (short)f2bf(f5_),\
                          (short)f2bf(f6_), (short)f2bf(f7_)};                 \
    *reinterpret_cast<short8*>(&AN[r * 64 + ((cgl ^ (r & 7)) * 8)]) = v8_;     \
} while (0)

#define COMPUTE(AN, BN) do {                                                   \
    _Pragma("unroll")                                                          \
    for (int s_ = 0; s_ < 2; ++s_) {                                           \
        short8 af_[4], bf_[4];                                                 \
        _Pragma("unroll")                                                      \
        for (int m_ = 0; m_ < 4; ++m_) {                                       \
            int ar_ = m_ * 16 + l16;                                           \
            af_[m_] = *reinterpret_cast<const short8*>(                        \
                &AN[ar_ * 64 + (((s_ * 4 + quad) ^ (ar_ & 7)) * 8)]);          \
        }                                                                      \
        _Pragma("unroll")                                                      \
        for (int n_ = 0; n_ < 4; ++n_) {                                       \
            int br_ = w * 64 + n_ * 16 + l16;                                  \
            bf_[n_] = *reinterpret_cast<const short8*>(                        \
                &BN[br_ * 64 + (((s_ * 4 + quad) ^ (br_ & 7)) * 8)]);          \
        }                                                                      \
        _Pragma("unroll")                                                      \
        for (int m_ = 0; m_ < 4; ++m_)                                         \
            _Pragma("unroll")                                                  \
            for (int n_ = 0; n_ < 4; ++n_)                                     \
                acc[m_][n_] = __builtin_amdgcn_mfma_f32_16x16x32_bf16(         \
                    af_[m_], bf_[n_], acc[m_][n_], 0, 0, 0);                   \
    }                                                                          \
} while (0)

    // ---- prologue: tile 0 -> A0/B0, prefetch R(1) ----
    LOAD_A(0);                  // 6 vm
    STAGE_B(B0, 0);             // 8 vm
    SCHED0;
    WRITE_A(A0);                // compiler auto-waits for R(0)
    SCHED0;
    LOAD_A(1);                  // 6 vm  (FIFO: [B0:8, R1:6])
    SCHED0;
    WAITVM6;                    // drain B0, keep R(1) in flight
    WAITLG;
    BAR;
    SCHED0;

    // ---- steady loop: kt = 0..59, unroll x2 for static buffer names ----
    for (int kt = 0; kt < 60; kt += 2) {
        // even: compute kt from A0/B0; stage kt+1 -> A1/B1; prefetch R(kt+2)
        STAGE_B(B1, kt + 1);    // 8 vm   (FIFO: [R(kt+1):6, B:8])
        SCHED0;
        COMPUTE(A0, B0);
        WRITE_A(A1);            // auto-wait -> R(kt+1) done
        SCHED0;
        LOAD_A(kt + 2);         // 6 vm   (FIFO: [B:8, R:6])
        SCHED0;
        WAITVM6;                // drain B(kt+1), keep R(kt+2)
        WAITLG;
        BAR;
        SCHED0;
        // odd: compute kt+1 from A1/B1; stage kt+2 -> A0/B0; prefetch R(kt+3)
        STAGE_B(B0, kt + 2);
        SCHED0;
        COMPUTE(A1, B1);
        WRITE_A(A0);
        SCHED0;
        LOAD_A(kt + 3);
        SCHED0;
        WAITVM6;
        WAITLG;
        BAR;
        SCHED0;
    }

    // ---- peel kt=60: compute A0/B0, stage tile 61 -> A1/B1 (R(61) in regs) ----
    STAGE_B(B1, 61);
    SCHED0;
    COMPUTE(A0, B0);
    WRITE_A(A1);                // consumes R(61)
    SCHED0;
    WAITVM0;
    WAITLG;
    BAR;
    SCHED0;

    // ---- tail: tiles 61..65; A for 62..65 from T2; pipelined staging ----
    STAGE_T(A0, 62); STAGE_B(B0, 62); SCHED0;
    COMPUTE(A1, B1);            // tile 61
    WAITVM0; WAITLG; BAR; SCHED0;
    STAGE_T(A1, 63); STAGE_B(B1, 63); SCHED0;
    COMPUTE(A0, B0);            // tile 62
    WAITVM0; WAITLG; BAR; SCHED0;
    STAGE_T(A0, 64); STAGE_B(B0, 64); SCHED0;
    COMPUTE(A1, B1);            // tile 63
    WAITVM0; WAITLG; BAR; SCHED0;
    STAGE_T(A1, 65); STAGE_B(B1, 65); SCHED0;
    COMPUTE(A0, B0);            // tile 64
    WAITVM0; WAITLG; BAR; SCHED0;
    COMPUTE(A1, B1);            // tile 65

#pragma unroll
    for (int m = 0; m < 4; ++m) {
#pragma unroll
        for (int n = 0; n < 4; ++n) {
            int col_l = w * 64 + n * 16 + l16;
            float bv = bias[b * DLAT + col_l];
#pragma unroll
            for (int rr = 0; rr < 4; ++rr) {
                int row_l = m * 16 + quad * 4 + rr;
                float v = acc[m][n][rr] + bv;
                v = v >= 0.f ? v : 0.3f * v;
                out[(size_t)(row0 + row_l) * OUTC + b * DLAT + col_l] = v;
            }
        }
    }
#undef STAGE_B
#undef STAGE_T
#undef LOAD_A
#undef WRITE_A
#undef COMPUTE
}

// ---------------------------------------------------------------------------
// FALLBACK (ws too small): verified kernels, unchanged.
// ---------------------------------------------------------------------------
__global__ void prep_w(const float* __restrict__ W, unsigned short* __restrict__ Wp) {
    __shared__ unsigned short tile[64 * 68];
    int bid = blockIdx.x;
    int nt = bid & 7;
    int t2 = bid >> 3;
    int kt = t2 % 66;
    int b  = t2 / 66;
    int tid = threadIdx.x;
    int n0 = nt * 64;
    int k0 = kt * 64;
#pragma unroll
    for (int i = 0; i < 4; ++i) {
        int c = i * 256 + tid;
        int r = c >> 4;
        int q = (c & 15) * 4;
        int pk = k0 + r;
        int wr = (pk < DIN) ? pk : ((pk >= 4032 && pk < 4168) ? pk - 32 : -1);
        float4 v = make_float4(0.f, 0.f, 0.f, 0.f);
        if (wr >= 0)
            v = *reinterpret_cast<const float4*>(W + ((size_t)b * FANIN + wr) * DLAT + n0 + q);
        ushort4 u4 = make_ushort4(f2bf(v.x), f2bf(v.y), f2bf(v.z), f2bf(v.w));
        *reinterpret_cast<ushort4*>(&tile[r * 68 + q]) = u4;
    }
    __syncthreads();
#pragma unroll
    for (int i = 0; i < 2; ++i) {
        int c = i * 256 + tid;
        int nl = c >> 3;
        int kc = c & 7;
        unsigned short o[8];
#pragma unroll
        for (int j = 0; j < 8; ++j) o[j] = tile[(kc * 8 + j) * 68 + nl];
        *reinterpret_cast<short8*>(Wp + ((size_t)(b * DLAT + n0 + nl)) * KPAD + k0 + kc * 8) =
            *reinterpret_cast<const short8*>(o);
    }
}

__global__ void prep_t(const float* __restrict__ embed, const float* __restrict__ batches,
                       unsigned short* __restrict__ T) {
    int i  = blockIdx.x * 256 + threadIdx.x;
    int t  = i % TC;
    int nb = i / TC;
    int b  = nb & 3;
    int n  = nb >> 2;
    float v = 0.f;
    if (t < DE)            v = embed[(size_t)n * (NBLK * DE) + b * DE + t];
    else if (t < DE + DB)  v = batches[(size_t)n * DB + (t - DE)];
    T[i] = f2bf(v);
}

__global__ __launch_bounds__(256, 3) void gemm_k(
    const float* __restrict__ x, const int* __restrict__ mask,
    const float* __restrict__ mean, const float* __restrict__ bias,
    const unsigned short* __restrict__ Wp, const unsigned short* __restrict__ T,
    float* __restrict__ out) {
    __shared__ unsigned short Asm_[128 * 64];
    __shared__ unsigned short Bsm_[128 * 64];

    int bid = blockIdx.x;
    int nt  = bid & 3;
    int b   = (bid >> 2) & 3;
    int mt  = bid >> 4;
    int tid  = threadIdx.x;
    int lane = tid & 63;
    int w    = tid >> 6;
    int wm   = w >> 1;
    int wn   = w & 1;
    int quad = lane >> 4;
    int l16  = lane & 15;
    int row0 = mt * 128;
    int n0   = nt * 128;

    floatx4 acc[4][4];
#pragma unroll
    for (int m = 0; m < 4; ++m)
#pragma unroll
        for (int n = 0; n < 4; ++n) acc[m][n] = (floatx4){0.f, 0.f, 0.f, 0.f};

    for (int kt = 0; kt < NKT; ++kt) {
        if (kt < 63) {
#pragma unroll
            for (int i = 0; i < 4; ++i) {
                int c  = i * 256 + tid;
                int r  = c >> 3;
                int cg = c & 7;
                int col = kt * 64 + cg * 8;
                short8 v8 = (short8){0, 0, 0, 0, 0, 0, 0, 0};
                if (col < DIN) {
                    size_t gi = (size_t)(row0 + r) * XC + (size_t)b * DIN + col;
                    const float4* xp = reinterpret_cast<const float4*>(x + gi);
                    const int4*   mp = reinterpret_cast<const int4*>(mask + gi);
                    const float4* ep = reinterpret_cast<const float4*>(mean + b * DIN + col);
                    float4 x0 = xp[0], x1 = xp[1];
                    int4   m0 = mp[0], m1 = mp[1];
                    float4 e0 = ep[0], e1 = ep[1];
                    float f0 = m0.x ? x0.x - e0.x : 0.f;
                    float f1 = m0.y ? x0.y - e0.y : 0.f;
                    float f2 = m0.z ? x0.z - e0.z : 0.f;
                    float f3 = m0.w ? x0.w - e0.w : 0.f;
                    float f4 = m1.x ? x1.x - e1.x : 0.f;
                    float f5 = m1.y ? x1.y - e1.y : 0.f;
                    float f6 = m1.z ? x1.z - e1.z : 0.f;
                    float f7 = m1.w ? x1.w - e1.w : 0.f;
                    v8 = (short8){(short)f2bf(f0), (short)f2bf(f1), (short)f2bf(f2),
                                  (short)f2bf(f3), (short)f2bf(f4), (short)f2bf(f5),
                                  (short)f2bf(f6), (short)f2bf(f7)};
                }
                *reinterpret_cast<short8*>(&Asm_[r * 64 + ((cg ^ (r & 7)) * 8)]) = v8;
            }
        } else {
#pragma unroll
            for (int i = 0; i < 4; ++i) {
                int c  = i * 256 + tid;
                int r  = c >> 3;
                int cg = (c & 7) ^ (r & 7);
                async16(T + ((size_t)(row0 + r) * NBLK + b) * TC + (kt - 63) * 64 + cg * 8,
                        &Asm_[c * 8]);
            }
        }
#pragma unroll
        for (int i = 0; i < 4; ++i) {
            int c  = i * 256 + tid;
            int nl = c >> 3;
            int cg = (c & 7) ^ (nl & 7);
            async16(Wp + ((size_t)(b * DLAT + n0 + nl)) * KPAD + kt * 64 + cg * 8,
                    &Bsm_[c * 8]);
        }
        __syncthreads();
#pragma unroll
        for (int s = 0; s < 2; ++s) {
            short8 af[4], bfr[4];
#pragma unroll
            for (int m = 0; m < 4; ++m) {
                int ar = wm * 64 + m * 16 + l16;
                af[m] = *reinterpret_cast<const short8*>(
                    &Asm_[ar * 64 + (((s * 4 + quad) ^ (ar & 7)) * 8)]);
            }
#pragma unroll
            for (int n = 0; n < 4; ++n) {
                int br = wn * 64 + n * 16 + l16;
                bfr[n] = *reinterpret_cast<const short8*>(
                    &Bsm_[br * 64 + (((s * 4 + quad) ^ (br & 7)) * 8)]);
            }
#pragma unroll
            for (int m = 0; m < 4; ++m)
#pragma unroll
                for (int n = 0; n < 4; ++n)
                    acc[m][n] = __builtin_amdgcn_mfma_f32_16x16x32_bf16(
                        af[m], bfr[n], acc[m][n], 0, 0, 0);
        }
        __syncthreads();
    }

#pragma unroll
    for (int m = 0; m < 4; ++m) {
#pragma unroll
        for (int n = 0; n < 4; ++n) {
            int col_l = wn * 64 + n * 16 + l16;
            float bv = bias[b * DLAT + n0 + col_l];
#pragma unroll
            for (int r = 0; r < 4; ++r) {
                int row_l = wm * 64 + m * 16 + quad * 4 + r;
                float v = acc[m][n][r] + bv;
                v = v >= 0.f ? v : 0.3f * v;
                out[(size_t)(row0 + row_l) * OUTC + b * DLAT + n0 + col_l] = v;
            }
        }
    }
}

extern "C" void kernel_launch(void* const* d_in, const int* in_sizes, int n_in,
                              void* d_out, int out_size, void* d_ws, size_t ws_size,
                              hipStream_t stream) {
    const float* x       = (const float*)d_in[0];
    const int*   mask    = (const int*)d_in[1];
    const float* embed   = (const float*)d_in[2];
    const float* batches = (const float*)d_in[3];
    const float* mean    = (const float*)d_in[4];
    const float* W       = (const float*)d_in[5];
    const float* bias    = (const float*)d_in[6];
    float* out = (float*)d_out;

    unsigned short* Wp = (unsigned short*)d_ws;                 // 17.3 MB
    size_t wp_elems = (size_t)NBLK * DLAT * KPAD;               // 8,650,752
    size_t t2_elems = (size_t)NROWS * NBLK * T2C;               // 4,194,304 (8.4 MB)
    size_t need_fast = (wp_elems + t2_elems) * 2;               // ~25.7 MB

    if (ws_size >= need_fast) {
        unsigned short* T2 = Wp + wp_elems;
        prep_wt<<<dim3(PW_GRID + PT2_GRID), dim3(256), 0, stream>>>(
            W, Wp, x, mask, mean, embed, batches, T2);
        gemm_f<<<dim3(256), dim3(512), 0, stream>>>(
            x, mask, mean, bias, Wp, T2, out);
    } else {
        prep_w<<<dim3(PW_GRID), dim3(256), 0, stream>>>(W, Wp);
        unsigned short* T = Wp + wp_elems;                      // 6.3 MB
        prep_t<<<dim3(12288), dim3(256), 0, stream>>>(embed, batches, T);
        gemm_k<<<dim3(512), dim3(256), 0, stream>>>(x, mask, mean, bias, Wp, T, out);
    }
}